// Round 1
// baseline (882.309 us; speedup 1.0000x reference)
//
#include <hip/hip_runtime.h>

#define N_NODES  100000
#define N_EDGES  1600000
#define N_GRAPHS 64

// ---- workspace layout (element offsets, 4B elements) ----
// degi    [0, N)              in-degree (excl self-loop)
// fill    [N, 2N)             CSR fill counters
// cnt     [2N, 2N+64)         nodes per graph
// row_ptr [200064, 300065)
// dis     [300096, 400096)    rsqrt(deg+1)
// s       [400128, 600128)    x * dis   (float2 per node)
// csr_src [600128, 2200128)
// q       [2200128, 5400128)  per-node layer-2 message (32 f32)
#define OFF_FILL   N_NODES
#define OFF_CNT    (2*N_NODES)
#define OFF_ROWPTR 200064
#define OFF_DIS    300096
#define OFF_S      400128
#define OFF_CSR    600128
#define OFF_Q      2200128

__global__ void k_deg(const int* __restrict__ dst, const int* __restrict__ batch,
                      int* __restrict__ degi, int* __restrict__ cnt) {
  int i = blockIdx.x * 256 + threadIdx.x;
  if (i < N_EDGES) atomicAdd(&degi[dst[i]], 1);
  if (i < N_NODES) atomicAdd(&cnt[batch[i]], 1);
}

// single-block exclusive scan of degi -> row_ptr (N+1 entries)
__global__ void k_scan(const int* __restrict__ degi, int* __restrict__ row_ptr) {
  __shared__ int sums[16];
  __shared__ int carry_sh;
  int tid = threadIdx.x;
  int lane = tid & 63, wid = tid >> 6;
  if (tid == 0) carry_sh = 0;
  __syncthreads();
  for (int base = 0; base < N_NODES; base += 1024) {
    int i = base + tid;
    int v = (i < N_NODES) ? degi[i] : 0;
    int xv = v;
#pragma unroll
    for (int off = 1; off < 64; off <<= 1) {
      int y = __shfl_up(xv, off, 64);
      if (lane >= off) xv += y;
    }
    if (lane == 63) sums[wid] = xv;
    __syncthreads();
    if (wid == 0) {
      int sv = (lane < 16) ? sums[lane] : 0;
#pragma unroll
      for (int off = 1; off < 16; off <<= 1) {
        int y = __shfl_up(sv, off, 64);
        if (lane >= off) sv += y;
      }
      if (lane < 16) sums[lane] = sv;
    }
    __syncthreads();
    int waveoff = (wid > 0) ? sums[wid - 1] : 0;
    int carry = carry_sh;
    if (i < N_NODES) row_ptr[i] = carry + waveoff + xv - v;
    __syncthreads();
    if (tid == 0) carry_sh = carry + sums[15];
    __syncthreads();
  }
  if (tid == 0) row_ptr[N_NODES] = carry_sh;
}

// fill CSR (bucket by dst) + compute dis and s = x*dis
__global__ void k_fill_s(const int* __restrict__ src, const int* __restrict__ dst,
                         const float* __restrict__ x, const int* __restrict__ degi,
                         const int* __restrict__ row_ptr, int* __restrict__ fill,
                         int* __restrict__ csr_src, float* __restrict__ dis,
                         float2* __restrict__ s) {
  int i = blockIdx.x * 256 + threadIdx.x;
  if (i < N_EDGES) {
    int d = dst[i];
    int pos = row_ptr[d] + atomicAdd(&fill[d], 1);
    csr_src[pos] = src[i];
  }
  if (i < N_NODES) {
    float dv = rsqrtf((float)(degi[i] + 1));
    dis[i] = dv;
    float2 xv = ((const float2*)x)[i];
    s[i] = make_float2(xv.x * dv, xv.y * dv);
  }
}

// layer 1 fused: gather s over in-edges, t = dis*(sum+self), then
// q[v] = dis[v] * relu(t@W1 + b1) @ W2   (one thread per node)
__global__ void k_layer1(const float2* __restrict__ s, const float* __restrict__ dis,
                         const int* __restrict__ row_ptr, const int* __restrict__ csr_src,
                         const float* __restrict__ W1, const float* __restrict__ b1,
                         const float* __restrict__ W2, float* __restrict__ q) {
  __shared__ float sW1[128];
  __shared__ float sb1[64];
  __shared__ float sW2[2048];
  int tid = threadIdx.x;
  for (int i = tid; i < 128; i += 256) sW1[i] = W1[i];
  for (int i = tid; i < 64; i += 256) sb1[i] = b1[i];
  for (int i = tid; i < 2048; i += 256) sW2[i] = W2[i];
  __syncthreads();
  int v = blockIdx.x * 256 + tid;
  if (v >= N_NODES) return;
  int beg = row_ptr[v], end = row_ptr[v + 1];
  float2 sv = s[v];
  float t0 = sv.x, t1 = sv.y;
  for (int k = beg; k < end; ++k) {
    float2 su = s[csr_src[k]];
    t0 += su.x;
    t1 += su.y;
  }
  float dv = dis[v];
  t0 *= dv;
  t1 *= dv;
  float acc[32];
#pragma unroll
  for (int m = 0; m < 32; ++m) acc[m] = 0.f;
  for (int j = 0; j < 64; ++j) {
    float r = fmaxf(fmaf(t0, sW1[j], fmaf(t1, sW1[64 + j], sb1[j])), 0.f);
#pragma unroll
    for (int m = 0; m < 32; ++m) acc[m] = fmaf(r, sW2[j * 32 + m], acc[m]);
  }
  float* qv = &q[v * 32];
#pragma unroll
  for (int m = 0; m < 32; ++m) qv[m] = acc[m] * dv;
}

// layer 2 + pooling: half-wave (32 lanes) per 8-node chunk; lane = feature.
__global__ void k_layer2(const float* __restrict__ q, const float* __restrict__ dis,
                         const int* __restrict__ row_ptr, const int* __restrict__ csr_src,
                         const float* __restrict__ b2, const int* __restrict__ batch,
                         float* __restrict__ out) {
  int tid = blockIdx.x * 256 + threadIdx.x;
  int lane = tid & 31;
  int hw = tid >> 5;
  int vbeg = hw * 8;
  if (vbeg >= N_NODES) return;
  int vend = min(vbeg + 8, N_NODES);
  float bm = b2[lane];
  float acc = 0.f;
  int curg = batch[vbeg];
  for (int v = vbeg; v < vend; ++v) {
    int g = batch[v];
    if (g != curg) {
      atomicAdd(&out[curg * 32 + lane], acc);
      acc = 0.f;
      curg = g;
    }
    int beg = row_ptr[v], end = row_ptr[v + 1];
    float z = q[v * 32 + lane];
    for (int k = beg; k < end; ++k) {
      int u = csr_src[k];
      z += q[u * 32 + lane];
    }
    acc += fmaf(z, dis[v], bm);
  }
  atomicAdd(&out[curg * 32 + lane], acc);
}

__global__ void k_final(float* __restrict__ out, const int* __restrict__ cnt) {
  int i = blockIdx.x * 256 + threadIdx.x;
  if (i < N_GRAPHS * 32) {
    int g = i >> 5;
    float c = (float)max(cnt[g], 1);
    out[i] /= c;
  }
}

extern "C" void kernel_launch(void* const* d_in, const int* in_sizes, int n_in,
                              void* d_out, int out_size, void* d_ws, size_t ws_size,
                              hipStream_t stream) {
  (void)in_sizes; (void)n_in; (void)out_size; (void)ws_size;
  const float* x   = (const float*)d_in[0];
  const float* W1  = (const float*)d_in[1];
  const float* b1  = (const float*)d_in[2];
  const float* W2  = (const float*)d_in[3];
  const float* b2  = (const float*)d_in[4];
  const int* edge  = (const int*)d_in[5];
  const int* batch = (const int*)d_in[6];
  const int* src = edge;             // edge_index[0]
  const int* dst = edge + N_EDGES;   // edge_index[1]
  float* out = (float*)d_out;

  int* ws       = (int*)d_ws;
  int* degi     = ws;
  int* fill     = ws + OFF_FILL;
  int* cnt      = ws + OFF_CNT;
  int* row_ptr  = ws + OFF_ROWPTR;
  float* dis    = (float*)(ws + OFF_DIS);
  float2* s     = (float2*)(ws + OFF_S);
  int* csr_src  = ws + OFF_CSR;
  float* q      = (float*)(ws + OFF_Q);

  hipMemsetAsync(degi, 0, (size_t)(2 * N_NODES + 64) * sizeof(int), stream);
  hipMemsetAsync(out, 0, (size_t)(N_GRAPHS * 32) * sizeof(float), stream);

  k_deg<<<(N_EDGES + 255) / 256, 256, 0, stream>>>(dst, batch, degi, cnt);
  k_scan<<<1, 1024, 0, stream>>>(degi, row_ptr);
  k_fill_s<<<(N_EDGES + 255) / 256, 256, 0, stream>>>(src, dst, x, degi, row_ptr,
                                                      fill, csr_src, dis, s);
  k_layer1<<<(N_NODES + 255) / 256, 256, 0, stream>>>(s, dis, row_ptr, csr_src,
                                                      W1, b1, W2, q);
  const int halfwaves = (N_NODES + 7) / 8;          // 12500
  const int threads2 = halfwaves * 32;              // 400000
  k_layer2<<<(threads2 + 255) / 256, 256, 0, stream>>>(q, dis, row_ptr, csr_src,
                                                       b2, batch, out);
  k_final<<<8, 256, 0, stream>>>(out, cnt);
}

// Round 2
// 184.055 us; speedup vs baseline: 4.7937x; 4.7937x over previous
//
#include <hip/hip_runtime.h>

#define N_NODES  100000
#define N_EDGES  1600000
#define N_GRAPHS 64
#define NBUCK    391                 // ceil(N_NODES / 256)
#define NBLK     256
#define CHUNK    (N_EDGES / NBLK)    // 6250 exactly

// ---- workspace layout (int elements). q overlays the sort scratch, which is
// dead after k_fine. Total = 5,200,384 ints = 20.8 MB.
#define OFF_GSTART 0            // 65   -> pad 128
#define OFF_ROWPTR 128          // 100,001 -> pad 100,096
#define OFF_DIS    100224       // 100,000 -> pad 100,096
#define OFF_S      200320       // 200,000 (float2 aligned) -> pad 200,064
#define OFF_CSR    400384       // 1,600,000
#define OFF_Q      2000384      // 3,200,000 (overlays BHIST..TMP)
#define OFF_BHIST  2000384      // 391*256 -> pad 100,352
#define OFF_BOFFL  2100736      // 100,352
#define OFF_BSUM   2201088      // 391 -> pad 512
#define OFF_BSTART 2201600      // 392 -> pad 512
#define OFF_TMP    2202112      // 1,600,000 (ends 3,802,112 < 5,200,384)

// ---------- scan helpers (block-uniform call sites only) ----------
__device__ __forceinline__ int excl_scan_256(int v, int* wsum) {
  int t = threadIdx.x, lane = t & 63, w = t >> 6;
  int x = v;
#pragma unroll
  for (int off = 1; off < 64; off <<= 1) {
    int y = __shfl_up(x, off, 64);
    if (lane >= off) x += y;
  }
  if (lane == 63) wsum[w] = x;
  __syncthreads();
  if (t == 0) {
    int r = 0;
#pragma unroll
    for (int i = 0; i < 4; ++i) { int tv = wsum[i]; wsum[i] = r; r += tv; }
  }
  __syncthreads();
  return x - v + wsum[w];
}

__device__ __forceinline__ int excl_scan_512(int v, int* wsum) {
  int t = threadIdx.x, lane = t & 63, w = t >> 6;
  int x = v;
#pragma unroll
  for (int off = 1; off < 64; off <<= 1) {
    int y = __shfl_up(x, off, 64);
    if (lane >= off) x += y;
  }
  if (lane == 63) wsum[w] = x;
  __syncthreads();
  if (t == 0) {
    int r = 0;
#pragma unroll
    for (int i = 0; i < 8; ++i) { int tv = wsum[i]; wsum[i] = r; r += tv; }
  }
  __syncthreads();
  return x - v + wsum[w];
}

// ---------- pass 1: per-block coarse histogram (LDS atomics only) ----------
__global__ void k_hist(const int* __restrict__ dst, int* __restrict__ bhist) {
  __shared__ int hist[NBUCK];
  int t = threadIdx.x, k = blockIdx.x;
  for (int b = t; b < NBUCK; b += 256) hist[b] = 0;
  __syncthreads();
  int e0 = k * CHUNK, e1 = e0 + CHUNK;
  for (int e = e0 + t; e < e1; e += 256) atomicAdd(&hist[dst[e] >> 8], 1);
  __syncthreads();
  for (int b = t; b < NBUCK; b += 256) bhist[b * NBLK + k] = hist[b];
}

// ---------- graph boundaries from sorted batch (atomic-free) ----------
__global__ void k_bounds(const int* __restrict__ batch, int* __restrict__ gstart) {
  int i = blockIdx.x * 256 + threadIdx.x;
  if (i >= N_NODES) return;
  int bi = batch[i];
  if (i == 0) {
    for (int g = 0; g <= bi; ++g) gstart[g] = 0;
  } else {
    int bp = batch[i - 1];
    for (int g = bp + 1; g <= bi; ++g) gstart[g] = i;
  }
  if (i == N_NODES - 1) {
    for (int g = bi + 1; g <= N_GRAPHS; ++g) gstart[g] = N_NODES;
  }
}

// ---------- pass 2a: scan each bucket's per-block counts ----------
__global__ void k_scan_a(const int* __restrict__ bhist, int* __restrict__ boffl,
                         int* __restrict__ bsum) {
  __shared__ int wsum[4];
  int t = threadIdx.x, b = blockIdx.x;
  int v = bhist[b * NBLK + t];
  int ex = excl_scan_256(v, wsum);
  boffl[b * NBLK + t] = ex;
  if (t == NBLK - 1) bsum[b] = ex + v;
}

// ---------- pass 2b: scan bucket totals -> bstart[0..NBUCK] ----------
__global__ void k_scan_b(const int* __restrict__ bsum, int* __restrict__ bstart) {
  __shared__ int wsum[8];
  int t = threadIdx.x;
  int v = (t < NBUCK) ? bsum[t] : 0;
  int ex = excl_scan_512(v, wsum);
  if (t <= NBUCK) bstart[t] = ex;
}

// ---------- pass 3: scatter edges into coarse buckets (LDS atomics only) ----
__global__ void k_scatter(const int* __restrict__ src, const int* __restrict__ dst,
                          const int* __restrict__ bstart, const int* __restrict__ boffl,
                          int* __restrict__ tmp) {
  __shared__ int sbase[NBUCK];
  __shared__ int fill[NBUCK];
  int t = threadIdx.x, k = blockIdx.x;
  for (int b = t; b < NBUCK; b += 256) {
    sbase[b] = bstart[b] + boffl[b * NBLK + k];
    fill[b] = 0;
  }
  __syncthreads();
  int e0 = k * CHUNK, e1 = e0 + CHUNK;
  for (int e = e0 + t; e < e1; e += 256) {
    int s_ = src[e], d_ = dst[e];
    int b = d_ >> 8;
    int pos = sbase[b] + atomicAdd(&fill[b], 1);
    tmp[pos] = (s_ << 8) | (d_ & 255);
  }
}

// ---------- pass 4: per-bucket fine CSR + dis + s (LDS atomics only) -------
__global__ void k_fine(const int* __restrict__ tmp, const int* __restrict__ bstart,
                       const float* __restrict__ x, int* __restrict__ csr_src,
                       int* __restrict__ row_ptr, float* __restrict__ dis,
                       float2* __restrict__ s) {
  __shared__ int hist[256];   // becomes lsc after scan
  __shared__ int fill[256];
  __shared__ int wsum[4];
  int t = threadIdx.x, b = blockIdx.x;
  int base_n = b << 8;
  int e0 = bstart[b], e1 = bstart[b + 1];
  hist[t] = 0;
  __syncthreads();
  for (int e = e0 + t; e < e1; e += 256) atomicAdd(&hist[tmp[e] & 255], 1);
  __syncthreads();
  int h = hist[t];
  int ex = excl_scan_256(h, wsum);
  hist[t] = ex;        // lsc
  fill[t] = 0;
  int nn = min(256, N_NODES - base_n);
  if (t < nn) {
    int v = base_n + t;
    row_ptr[v] = e0 + ex;
    float dv = rsqrtf((float)(h + 1));
    dis[v] = dv;
    float2 xv = s ? ((const float2*)x)[v] : make_float2(0.f, 0.f);
    s[v] = make_float2(xv.x * dv, xv.y * dv);
  }
  if (b == NBUCK - 1 && t == 0) row_ptr[N_NODES] = e1;
  __syncthreads();
  for (int e = e0 + t; e < e1; e += 256) {
    int p = tmp[e];
    int fine = p & 255;
    int pos = e0 + hist[fine] + atomicAdd(&fill[fine], 1);
    csr_src[pos] = p >> 8;
  }
}

// ---------- layer 1 fused: t = dis*(sum s + self); q = dis * relu(t@W1+b1)@W2
__global__ void k_layer1(const float2* __restrict__ s, const float* __restrict__ dis,
                         const int* __restrict__ row_ptr, const int* __restrict__ csr_src,
                         const float* __restrict__ W1, const float* __restrict__ b1,
                         const float* __restrict__ W2, float* __restrict__ q) {
  __shared__ float sW1[128];
  __shared__ float sb1[64];
  __shared__ float sW2[2048];
  int tid = threadIdx.x;
  for (int i = tid; i < 128; i += 256) sW1[i] = W1[i];
  for (int i = tid; i < 64; i += 256) sb1[i] = b1[i];
  for (int i = tid; i < 2048; i += 256) sW2[i] = W2[i];
  __syncthreads();
  int v = blockIdx.x * 256 + tid;
  if (v >= N_NODES) return;
  int beg = row_ptr[v], end = row_ptr[v + 1];
  float2 sv = s[v];
  float t0 = sv.x, t1 = sv.y;
  for (int k = beg; k < end; ++k) {
    float2 su = s[csr_src[k]];
    t0 += su.x;
    t1 += su.y;
  }
  float dv = dis[v];
  t0 *= dv;
  t1 *= dv;
  float acc[32];
#pragma unroll
  for (int m = 0; m < 32; ++m) acc[m] = 0.f;
  for (int j = 0; j < 64; ++j) {
    float r = fmaxf(fmaf(t0, sW1[j], fmaf(t1, sW1[64 + j], sb1[j])), 0.f);
#pragma unroll
    for (int m = 0; m < 32; ++m) acc[m] = fmaf(r, sW2[j * 32 + m], acc[m]);
  }
  float* qv = &q[v * 32];
#pragma unroll
  for (int m = 0; m < 32; ++m) qv[m] = acc[m] * dv;
}

// ---------- layer 2 + pooling: halfwave=8 nodes, block=64 nodes ------------
__global__ void k_layer2(const float* __restrict__ q, const float* __restrict__ dis,
                         const int* __restrict__ row_ptr, const int* __restrict__ csr_src,
                         const int* __restrict__ batch, float* __restrict__ pooled) {
  __shared__ float red[8 * 32];
  int t = threadIdx.x, lane = t & 31, hwl = t >> 5;
  int vb_blk = blockIdx.x * 64;
  int nlast = min(vb_blk + 63, N_NODES - 1);
  bool uniform = (batch[vb_blk] == batch[nlast]);   // block-uniform predicate
  int v0 = vb_blk + hwl * 8;
  int v1 = min(v0 + 8, N_NODES);
  float acc = 0.f;
  int curg = (v0 < N_NODES) ? batch[v0] : -1;
  for (int v = v0; v < v1; ++v) {
    if (!uniform) {
      int g = batch[v];
      if (g != curg) { atomicAdd(&pooled[curg * 32 + lane], acc); acc = 0.f; curg = g; }
    }
    float z = q[v * 32 + lane];
    int e0 = row_ptr[v], e1 = row_ptr[v + 1];
    for (int k = e0; k < e1; ++k) z += q[csr_src[k] * 32 + lane];
    acc = fmaf(z, dis[v], acc);
  }
  if (uniform) {
    red[t] = acc;
    __syncthreads();
    if (hwl == 0) {
      float ssum = acc;
#pragma unroll
      for (int h = 1; h < 8; ++h) ssum += red[h * 32 + lane];
      atomicAdd(&pooled[batch[vb_blk] * 32 + lane], ssum);
    }
  } else if (curg >= 0) {
    atomicAdd(&pooled[curg * 32 + lane], acc);
  }
}

// ---------- final: mean + b2 ----------
__global__ void k_final(float* __restrict__ out, const int* __restrict__ gstart,
                        const float* __restrict__ b2) {
  int i = blockIdx.x * 256 + threadIdx.x;
  if (i < N_GRAPHS * 32) {
    int g = i >> 5, l = i & 31;
    int c = gstart[g + 1] - gstart[g];
    out[i] = (c > 0) ? out[i] / (float)c + b2[l] : 0.f;
  }
}

extern "C" void kernel_launch(void* const* d_in, const int* in_sizes, int n_in,
                              void* d_out, int out_size, void* d_ws, size_t ws_size,
                              hipStream_t stream) {
  (void)in_sizes; (void)n_in; (void)out_size; (void)ws_size;
  const float* x   = (const float*)d_in[0];
  const float* W1  = (const float*)d_in[1];
  const float* b1  = (const float*)d_in[2];
  const float* W2  = (const float*)d_in[3];
  const float* b2  = (const float*)d_in[4];
  const int* edge  = (const int*)d_in[5];
  const int* batch = (const int*)d_in[6];
  const int* src = edge;             // edge_index[0]
  const int* dst = edge + N_EDGES;   // edge_index[1]
  float* out = (float*)d_out;

  int* ws      = (int*)d_ws;
  int* gstart  = ws + OFF_GSTART;
  int* row_ptr = ws + OFF_ROWPTR;
  float* dis   = (float*)(ws + OFF_DIS);
  float2* s    = (float2*)(ws + OFF_S);
  int* csr_src = ws + OFF_CSR;
  float* q     = (float*)(ws + OFF_Q);
  int* bhist   = ws + OFF_BHIST;
  int* boffl   = ws + OFF_BOFFL;
  int* bsum    = ws + OFF_BSUM;
  int* bstart  = ws + OFF_BSTART;
  int* tmp     = ws + OFF_TMP;

  hipMemsetAsync(out, 0, (size_t)(N_GRAPHS * 32) * sizeof(float), stream);

  k_hist<<<NBLK, 256, 0, stream>>>(dst, bhist);
  k_bounds<<<(N_NODES + 255) / 256, 256, 0, stream>>>(batch, gstart);
  k_scan_a<<<NBUCK, 256, 0, stream>>>(bhist, boffl, bsum);
  k_scan_b<<<1, 512, 0, stream>>>(bsum, bstart);
  k_scatter<<<NBLK, 256, 0, stream>>>(src, dst, bstart, boffl, tmp);
  k_fine<<<NBUCK, 256, 0, stream>>>(tmp, bstart, x, csr_src, row_ptr, dis, s);
  k_layer1<<<(N_NODES + 255) / 256, 256, 0, stream>>>(s, dis, row_ptr, csr_src,
                                                      W1, b1, W2, q);
  k_layer2<<<(N_NODES + 63) / 64, 256, 0, stream>>>(q, dis, row_ptr, csr_src,
                                                    batch, out);
  k_final<<<8, 256, 0, stream>>>(out, gstart, b2);
}

// Round 3
// 110.613 us; speedup vs baseline: 7.9766x; 1.6640x over previous
//
#include <hip/hip_runtime.h>
#include <hip/hip_fp16.h>

#define N_NODES  100000
#define N_EDGES  1600000
#define N_GRAPHS 64
#define NBUCK    391                 // ceil(N_NODES / 256)
#define NBLK     256
#define CHUNK    (N_EDGES / NBLK)    // 6250 exactly

// ---- workspace layout (int elements). q (fp16, 1.6M ints) overlays the sort
// scratch, which is dead after k_fine.
#define OFF_GSTART 0            // 65   -> pad 128
#define OFF_ROWPTR 128          // 100,001 -> pad 100,096
#define OFF_DIS    100224       // 100,000 -> pad 100,096
#define OFF_S      200320       // 200,000 (float2 aligned) -> pad 200,064
#define OFF_CSR    400384       // 1,600,000
#define OFF_Q      2000384      // 1,600,000 ints of half2 (overlays BHIST..TMP)
#define OFF_BHIST  2000384      // 391*256 -> pad 100,352
#define OFF_BOFFL  2100736      // 100,352
#define OFF_BSUM   2201088      // 391 -> pad 512
#define OFF_BSTART 2201600      // 392 -> pad 512
#define OFF_TMP    2202112      // 1,600,000 (ends 3,802,112)

// ---------- scan helpers (block-uniform call sites only) ----------
__device__ __forceinline__ int excl_scan_256(int v, int* wsum) {
  int t = threadIdx.x, lane = t & 63, w = t >> 6;
  int x = v;
#pragma unroll
  for (int off = 1; off < 64; off <<= 1) {
    int y = __shfl_up(x, off, 64);
    if (lane >= off) x += y;
  }
  if (lane == 63) wsum[w] = x;
  __syncthreads();
  if (t == 0) {
    int r = 0;
#pragma unroll
    for (int i = 0; i < 4; ++i) { int tv = wsum[i]; wsum[i] = r; r += tv; }
  }
  __syncthreads();
  return x - v + wsum[w];
}

__device__ __forceinline__ int excl_scan_512(int v, int* wsum) {
  int t = threadIdx.x, lane = t & 63, w = t >> 6;
  int x = v;
#pragma unroll
  for (int off = 1; off < 64; off <<= 1) {
    int y = __shfl_up(x, off, 64);
    if (lane >= off) x += y;
  }
  if (lane == 63) wsum[w] = x;
  __syncthreads();
  if (t == 0) {
    int r = 0;
#pragma unroll
    for (int i = 0; i < 8; ++i) { int tv = wsum[i]; wsum[i] = r; r += tv; }
  }
  __syncthreads();
  return x - v + wsum[w];
}

// ---------- pass 1: per-block coarse histogram (LDS atomics only) ----------
__global__ void k_hist(const int* __restrict__ dst, int* __restrict__ bhist) {
  __shared__ int hist[NBUCK];
  int t = threadIdx.x, k = blockIdx.x;
  for (int b = t; b < NBUCK; b += 256) hist[b] = 0;
  __syncthreads();
  int e0 = k * CHUNK, e1 = e0 + CHUNK;
  for (int e = e0 + t; e < e1; e += 256) atomicAdd(&hist[dst[e] >> 8], 1);
  __syncthreads();
  for (int b = t; b < NBUCK; b += 256) bhist[b * NBLK + k] = hist[b];
}

// ---------- graph boundaries from sorted batch (atomic-free) ----------
__global__ void k_bounds(const int* __restrict__ batch, int* __restrict__ gstart) {
  int i = blockIdx.x * 256 + threadIdx.x;
  if (i >= N_NODES) return;
  int bi = batch[i];
  if (i == 0) {
    for (int g = 0; g <= bi; ++g) gstart[g] = 0;
  } else {
    int bp = batch[i - 1];
    for (int g = bp + 1; g <= bi; ++g) gstart[g] = i;
  }
  if (i == N_NODES - 1) {
    for (int g = bi + 1; g <= N_GRAPHS; ++g) gstart[g] = N_NODES;
  }
}

// ---------- pass 2a: scan each bucket's per-block counts ----------
__global__ void k_scan_a(const int* __restrict__ bhist, int* __restrict__ boffl,
                         int* __restrict__ bsum) {
  __shared__ int wsum[4];
  int t = threadIdx.x, b = blockIdx.x;
  int v = bhist[b * NBLK + t];
  int ex = excl_scan_256(v, wsum);
  boffl[b * NBLK + t] = ex;
  if (t == NBLK - 1) bsum[b] = ex + v;
}

// ---------- pass 2b: scan bucket totals -> bstart[0..NBUCK] ----------
__global__ void k_scan_b(const int* __restrict__ bsum, int* __restrict__ bstart) {
  __shared__ int wsum[8];
  int t = threadIdx.x;
  int v = (t < NBUCK) ? bsum[t] : 0;
  int ex = excl_scan_512(v, wsum);
  if (t <= NBUCK) bstart[t] = ex;
}

// ---------- pass 3: scatter edges into coarse buckets (LDS atomics only) ----
__global__ void k_scatter(const int* __restrict__ src, const int* __restrict__ dst,
                          const int* __restrict__ bstart, const int* __restrict__ boffl,
                          int* __restrict__ tmp) {
  __shared__ int sbase[NBUCK];
  __shared__ int fill[NBUCK];
  int t = threadIdx.x, k = blockIdx.x;
  for (int b = t; b < NBUCK; b += 256) {
    sbase[b] = bstart[b] + boffl[b * NBLK + k];
    fill[b] = 0;
  }
  __syncthreads();
  int e0 = k * CHUNK, e1 = e0 + CHUNK;
  for (int e = e0 + t; e < e1; e += 256) {
    int s_ = src[e], d_ = dst[e];
    int b = d_ >> 8;
    int pos = sbase[b] + atomicAdd(&fill[b], 1);
    tmp[pos] = (s_ << 8) | (d_ & 255);
  }
}

// ---------- pass 4: per-bucket fine CSR + dis + s (LDS atomics only) -------
__global__ void k_fine(const int* __restrict__ tmp, const int* __restrict__ bstart,
                       const float* __restrict__ x, int* __restrict__ csr_src,
                       int* __restrict__ row_ptr, float* __restrict__ dis,
                       float2* __restrict__ s) {
  __shared__ int hist[256];   // becomes lsc after scan
  __shared__ int fill[256];
  __shared__ int wsum[4];
  int t = threadIdx.x, b = blockIdx.x;
  int base_n = b << 8;
  int e0 = bstart[b], e1 = bstart[b + 1];
  hist[t] = 0;
  __syncthreads();
  for (int e = e0 + t; e < e1; e += 256) atomicAdd(&hist[tmp[e] & 255], 1);
  __syncthreads();
  int h = hist[t];
  int ex = excl_scan_256(h, wsum);
  hist[t] = ex;        // lsc
  fill[t] = 0;
  int nn = min(256, N_NODES - base_n);
  if (t < nn) {
    int v = base_n + t;
    row_ptr[v] = e0 + ex;
    float dv = rsqrtf((float)(h + 1));
    dis[v] = dv;
    float2 xv = ((const float2*)x)[v];
    s[v] = make_float2(xv.x * dv, xv.y * dv);
  }
  if (b == NBUCK - 1 && t == 0) row_ptr[N_NODES] = e1;
  __syncthreads();
  for (int e = e0 + t; e < e1; e += 256) {
    int p = tmp[e];
    int fine = p & 255;
    int pos = e0 + hist[fine] + atomicAdd(&fill[fine], 1);
    csr_src[pos] = p >> 8;
  }
}

// ---------- layer 1 fused: t = dis*(sum s + self); q = fp16(dis*relu(t@W1+b1)@W2)
__global__ void k_layer1(const float2* __restrict__ s, const float* __restrict__ dis,
                         const int* __restrict__ row_ptr, const int* __restrict__ csr_src,
                         const float* __restrict__ W1, const float* __restrict__ b1,
                         const float* __restrict__ W2, __half2* __restrict__ qh) {
  __shared__ float sW1[128];
  __shared__ float sb1[64];
  __shared__ float sW2[2048];
  int tid = threadIdx.x;
  for (int i = tid; i < 128; i += 256) sW1[i] = W1[i];
  for (int i = tid; i < 64; i += 256) sb1[i] = b1[i];
  for (int i = tid; i < 2048; i += 256) sW2[i] = W2[i];
  __syncthreads();
  int v = blockIdx.x * 256 + tid;
  if (v >= N_NODES) return;
  int beg = row_ptr[v], end = row_ptr[v + 1];
  float2 sv = s[v];
  float t0 = sv.x, t1 = sv.y;
  int k = beg;
  for (; k + 4 <= end; k += 4) {
    int u0 = csr_src[k], u1 = csr_src[k + 1], u2 = csr_src[k + 2], u3 = csr_src[k + 3];
    float2 a = s[u0], b = s[u1], c = s[u2], d = s[u3];
    t0 += a.x + b.x + c.x + d.x;
    t1 += a.y + b.y + c.y + d.y;
  }
  for (; k < end; ++k) {
    float2 su = s[csr_src[k]];
    t0 += su.x;
    t1 += su.y;
  }
  float dv = dis[v];
  t0 *= dv;
  t1 *= dv;
  float acc[32];
#pragma unroll
  for (int m = 0; m < 32; ++m) acc[m] = 0.f;
  for (int j = 0; j < 64; ++j) {
    float r = fmaxf(fmaf(t0, sW1[j], fmaf(t1, sW1[64 + j], sb1[j])), 0.f);
#pragma unroll
    for (int m = 0; m < 32; ++m) acc[m] = fmaf(r, sW2[j * 32 + m], acc[m]);
  }
  int buf[16];
#pragma unroll
  for (int m = 0; m < 16; ++m) {
    __half2 h = __floats2half2_rn(acc[2 * m] * dv, acc[2 * m + 1] * dv);
    buf[m] = *reinterpret_cast<int*>(&h);
  }
  int4* dst4 = (int4*)&qh[v * 16];
  dst4[0] = make_int4(buf[0], buf[1], buf[2], buf[3]);
  dst4[1] = make_int4(buf[4], buf[5], buf[6], buf[7]);
  dst4[2] = make_int4(buf[8], buf[9], buf[10], buf[11]);
  dst4[3] = make_int4(buf[12], buf[13], buf[14], buf[15]);
}

// ---------- layer 2 + pooling: 16 lanes per node-row (half2/lane),
// 16 rowgroups per block, 4 nodes per rowgroup, 4-deep unrolled gather ------
__global__ void k_layer2(const __half2* __restrict__ qh, const float* __restrict__ dis,
                         const int* __restrict__ row_ptr, const int* __restrict__ csr_src,
                         const int* __restrict__ batch, float* __restrict__ pooled) {
  __shared__ float2 red[16][16];
  int t = threadIdx.x;
  int f2 = t & 15;          // feature pair
  int rg = t >> 4;          // rowgroup 0..15
  int vb = blockIdx.x * 64;
  int nlast = min(vb + 63, N_NODES - 1);
  bool uniform = (batch[vb] == batch[nlast]);
  int v0 = vb + rg * 4;
  int v1 = min(v0 + 4, N_NODES);
  float2 acc = make_float2(0.f, 0.f);
  int curg = (v0 < N_NODES) ? batch[v0] : -1;
  for (int v = v0; v < v1; ++v) {
    if (!uniform) {
      int g = batch[v];
      if (g != curg) {
        atomicAdd(&pooled[curg * 32 + 2 * f2], acc.x);
        atomicAdd(&pooled[curg * 32 + 2 * f2 + 1], acc.y);
        acc = make_float2(0.f, 0.f);
        curg = g;
      }
    }
    int e0 = row_ptr[v], e1 = row_ptr[v + 1];
    float2 z = __half22float2(qh[v * 16 + f2]);
    int k = e0;
    for (; k + 4 <= e1; k += 4) {
      int u0 = csr_src[k], u1 = csr_src[k + 1], u2 = csr_src[k + 2], u3 = csr_src[k + 3];
      __half2 a = qh[u0 * 16 + f2];
      __half2 b = qh[u1 * 16 + f2];
      __half2 c = qh[u2 * 16 + f2];
      __half2 d = qh[u3 * 16 + f2];
      float2 fa = __half22float2(a), fb = __half22float2(b);
      float2 fc = __half22float2(c), fd = __half22float2(d);
      z.x += (fa.x + fb.x) + (fc.x + fd.x);
      z.y += (fa.y + fb.y) + (fc.y + fd.y);
    }
    for (; k < e1; ++k) {
      float2 f = __half22float2(qh[csr_src[k] * 16 + f2]);
      z.x += f.x;
      z.y += f.y;
    }
    float dv = dis[v];
    acc.x = fmaf(z.x, dv, acc.x);
    acc.y = fmaf(z.y, dv, acc.y);
  }
  if (uniform) {
    red[rg][f2] = acc;
    __syncthreads();
    if (t < 16) {
      float2 ssum = make_float2(0.f, 0.f);
#pragma unroll
      for (int r = 0; r < 16; ++r) {
        ssum.x += red[r][t].x;
        ssum.y += red[r][t].y;
      }
      int g = batch[vb];
      atomicAdd(&pooled[g * 32 + 2 * t], ssum.x);
      atomicAdd(&pooled[g * 32 + 2 * t + 1], ssum.y);
    }
  } else if (curg >= 0) {
    atomicAdd(&pooled[curg * 32 + 2 * f2], acc.x);
    atomicAdd(&pooled[curg * 32 + 2 * f2 + 1], acc.y);
  }
}

// ---------- final: mean + b2 ----------
__global__ void k_final(float* __restrict__ out, const int* __restrict__ gstart,
                        const float* __restrict__ b2) {
  int i = blockIdx.x * 256 + threadIdx.x;
  if (i < N_GRAPHS * 32) {
    int g = i >> 5, l = i & 31;
    int c = gstart[g + 1] - gstart[g];
    out[i] = (c > 0) ? out[i] / (float)c + b2[l] : 0.f;
  }
}

extern "C" void kernel_launch(void* const* d_in, const int* in_sizes, int n_in,
                              void* d_out, int out_size, void* d_ws, size_t ws_size,
                              hipStream_t stream) {
  (void)in_sizes; (void)n_in; (void)out_size; (void)ws_size;
  const float* x   = (const float*)d_in[0];
  const float* W1  = (const float*)d_in[1];
  const float* b1  = (const float*)d_in[2];
  const float* W2  = (const float*)d_in[3];
  const float* b2  = (const float*)d_in[4];
  const int* edge  = (const int*)d_in[5];
  const int* batch = (const int*)d_in[6];
  const int* src = edge;             // edge_index[0]
  const int* dst = edge + N_EDGES;   // edge_index[1]
  float* out = (float*)d_out;

  int* ws      = (int*)d_ws;
  int* gstart  = ws + OFF_GSTART;
  int* row_ptr = ws + OFF_ROWPTR;
  float* dis   = (float*)(ws + OFF_DIS);
  float2* s    = (float2*)(ws + OFF_S);
  int* csr_src = ws + OFF_CSR;
  __half2* qh  = (__half2*)(ws + OFF_Q);
  int* bhist   = ws + OFF_BHIST;
  int* boffl   = ws + OFF_BOFFL;
  int* bsum    = ws + OFF_BSUM;
  int* bstart  = ws + OFF_BSTART;
  int* tmp     = ws + OFF_TMP;

  hipMemsetAsync(out, 0, (size_t)(N_GRAPHS * 32) * sizeof(float), stream);

  k_hist<<<NBLK, 256, 0, stream>>>(dst, bhist);
  k_bounds<<<(N_NODES + 255) / 256, 256, 0, stream>>>(batch, gstart);
  k_scan_a<<<NBUCK, 256, 0, stream>>>(bhist, boffl, bsum);
  k_scan_b<<<1, 512, 0, stream>>>(bsum, bstart);
  k_scatter<<<NBLK, 256, 0, stream>>>(src, dst, bstart, boffl, tmp);
  k_fine<<<NBUCK, 256, 0, stream>>>(tmp, bstart, x, csr_src, row_ptr, dis, s);
  k_layer1<<<(N_NODES + 255) / 256, 256, 0, stream>>>(s, dis, row_ptr, csr_src,
                                                      W1, b1, W2, qh);
  k_layer2<<<(N_NODES + 63) / 64, 256, 0, stream>>>(qh, dis, row_ptr, csr_src,
                                                    batch, out);
  k_final<<<8, 256, 0, stream>>>(out, gstart, b2);
}

// Round 4
// 105.353 us; speedup vs baseline: 8.3748x; 1.0499x over previous
//
#include <hip/hip_runtime.h>
#include <hip/hip_fp16.h>

#define N_NODES  100000
#define N_EDGES  1600000
#define N_GRAPHS 64
#define NBUCK    391                 // ceil(N_NODES / 256)
#define NBLK     256
#define CHUNK    (N_EDGES / NBLK)    // 6250 exactly
#define NODEBLK  1563                // ceil(N_NODES / 64)

// ---- workspace layout (int elements). q planes overlay the sort scratch,
// which is dead after k_fine. Max extent 3,802,112 ints = 15.2 MB.
#define OFF_GSTART 0            // 65   -> pad 128
#define OFF_ROWPTR 128          // 100,001 -> pad 100,096
#define OFF_DIS    100224       // 100,000 -> pad 100,096
#define OFF_S      200320       // 200,000 (float2 aligned) -> pad 200,064
#define OFF_CSR    400384       // 1,600,000
#define OFF_QLO    2000384      // 800,000 ints (100k x 8 half2) -> pad 800,128
#define OFF_QHI    2800512      // 800,000 ints
#define OFF_BHIST  2000384      // overlays QLO (dead after k_scan_a)
#define OFF_BOFFL  2100736      // 100,352
#define OFF_BSUM   2201088      // 391 -> pad 512
#define OFF_BSTART 2201600      // 392 -> pad 512
#define OFF_TMP    2202112      // 1,600,000 (dead after k_fine)

// ---------- scan helpers (block-uniform call sites only) ----------
__device__ __forceinline__ int excl_scan_256(int v, int* wsum) {
  int t = threadIdx.x, lane = t & 63, w = t >> 6;
  int x = v;
#pragma unroll
  for (int off = 1; off < 64; off <<= 1) {
    int y = __shfl_up(x, off, 64);
    if (lane >= off) x += y;
  }
  if (lane == 63) wsum[w] = x;
  __syncthreads();
  if (t == 0) {
    int r = 0;
#pragma unroll
    for (int i = 0; i < 4; ++i) { int tv = wsum[i]; wsum[i] = r; r += tv; }
  }
  __syncthreads();
  return x - v + wsum[w];
}

__device__ __forceinline__ int excl_scan_512(int v, int* wsum) {
  int t = threadIdx.x, lane = t & 63, w = t >> 6;
  int x = v;
#pragma unroll
  for (int off = 1; off < 64; off <<= 1) {
    int y = __shfl_up(x, off, 64);
    if (lane >= off) x += y;
  }
  if (lane == 63) wsum[w] = x;
  __syncthreads();
  if (t == 0) {
    int r = 0;
#pragma unroll
    for (int i = 0; i < 8; ++i) { int tv = wsum[i]; wsum[i] = r; r += tv; }
  }
  __syncthreads();
  return x - v + wsum[w];
}

// ---------- pass 1: per-block coarse histogram (LDS atomics only) ----------
__global__ void k_hist(const int* __restrict__ dst, int* __restrict__ bhist) {
  __shared__ int hist[NBUCK];
  int t = threadIdx.x, k = blockIdx.x;
  for (int b = t; b < NBUCK; b += 256) hist[b] = 0;
  __syncthreads();
  int e0 = k * CHUNK, e1 = e0 + CHUNK;
  for (int e = e0 + t; e < e1; e += 256) atomicAdd(&hist[dst[e] >> 8], 1);
  __syncthreads();
  for (int b = t; b < NBUCK; b += 256) bhist[b * NBLK + k] = hist[b];
}

// ---------- pass 2a: scan each bucket's per-block counts + graph bounds ----
__global__ void k_scan_a(const int* __restrict__ bhist, int* __restrict__ boffl,
                         int* __restrict__ bsum, const int* __restrict__ batch,
                         int* __restrict__ gstart) {
  __shared__ int wsum[4];
  int t = threadIdx.x, b = blockIdx.x;
  // fused graph-boundary detection (grid covers 100,096 >= N_NODES threads)
  int i = b * 256 + t;
  if (i < N_NODES) {
    int bi = batch[i];
    if (i == 0) {
      for (int g = 0; g <= bi; ++g) gstart[g] = 0;
    } else {
      int bp = batch[i - 1];
      for (int g = bp + 1; g <= bi; ++g) gstart[g] = i;
    }
    if (i == N_NODES - 1) {
      for (int g = bi + 1; g <= N_GRAPHS; ++g) gstart[g] = N_NODES;
    }
  }
  int v = bhist[b * NBLK + t];
  int ex = excl_scan_256(v, wsum);
  boffl[b * NBLK + t] = ex;
  if (t == NBLK - 1) bsum[b] = ex + v;
}

// ---------- pass 2b: scan bucket totals -> bstart; zero pooled output ------
__global__ void k_scan_b(const int* __restrict__ bsum, int* __restrict__ bstart,
                         float* __restrict__ pooled) {
  __shared__ int wsum[8];
  int t = threadIdx.x;
  for (int i = t; i < N_GRAPHS * 32; i += 512) pooled[i] = 0.f;
  int v = (t < NBUCK) ? bsum[t] : 0;
  int ex = excl_scan_512(v, wsum);
  if (t <= NBUCK) bstart[t] = ex;
}

// ---------- pass 3: scatter edges into coarse buckets (LDS atomics only) ----
__global__ void k_scatter(const int* __restrict__ src, const int* __restrict__ dst,
                          const int* __restrict__ bstart, const int* __restrict__ boffl,
                          int* __restrict__ tmp) {
  __shared__ int sbase[NBUCK];
  __shared__ int fill[NBUCK];
  int t = threadIdx.x, k = blockIdx.x;
  for (int b = t; b < NBUCK; b += 256) {
    sbase[b] = bstart[b] + boffl[b * NBLK + k];
    fill[b] = 0;
  }
  __syncthreads();
  int e0 = k * CHUNK, e1 = e0 + CHUNK;
  for (int e = e0 + t; e < e1; e += 256) {
    int s_ = src[e], d_ = dst[e];
    int b = d_ >> 8;
    int pos = sbase[b] + atomicAdd(&fill[b], 1);
    tmp[pos] = (s_ << 8) | (d_ & 255);
  }
}

// ---------- pass 4: per-bucket fine CSR + dis + s (LDS atomics only) -------
__global__ void k_fine(const int* __restrict__ tmp, const int* __restrict__ bstart,
                       const float* __restrict__ x, int* __restrict__ csr_src,
                       int* __restrict__ row_ptr, float* __restrict__ dis,
                       float2* __restrict__ s) {
  __shared__ int hist[256];   // becomes scanned offsets after scan
  __shared__ int fill[256];
  __shared__ int wsum[4];
  int t = threadIdx.x, b = blockIdx.x;
  int base_n = b << 8;
  int e0 = bstart[b], e1 = bstart[b + 1];
  hist[t] = 0;
  __syncthreads();
  for (int e = e0 + t; e < e1; e += 256) atomicAdd(&hist[tmp[e] & 255], 1);
  __syncthreads();
  int h = hist[t];
  int ex = excl_scan_256(h, wsum);
  hist[t] = ex;
  fill[t] = 0;
  int nn = min(256, N_NODES - base_n);
  if (t < nn) {
    int v = base_n + t;
    row_ptr[v] = e0 + ex;
    float dv = rsqrtf((float)(h + 1));
    dis[v] = dv;
    float2 xv = ((const float2*)x)[v];
    s[v] = make_float2(xv.x * dv, xv.y * dv);
  }
  if (b == NBUCK - 1 && t == 0) row_ptr[N_NODES] = e1;
  __syncthreads();
  for (int e = e0 + t; e < e1; e += 256) {
    int p = tmp[e];
    int fine = p & 255;
    int pos = e0 + hist[fine] + atomicAdd(&fill[fine], 1);
    csr_src[pos] = p >> 8;
  }
}

// ---------- layer 1 fused: t = dis*(sum s + self); q = fp16(dis*relu(t@W1+b1)@W2)
// weights read via float4 LDS broadcasts; output split into two 16-feature planes
__global__ void k_layer1(const float2* __restrict__ s, const float* __restrict__ dis,
                         const int* __restrict__ row_ptr, const int* __restrict__ csr_src,
                         const float* __restrict__ W1, const float* __restrict__ b1,
                         const float* __restrict__ W2, int4* __restrict__ q_lo,
                         int4* __restrict__ q_hi) {
  __shared__ float4 sWB[64];     // {W1[0][j], W1[1][j], b1[j], 0}
  __shared__ float4 sW2[512];    // W2 row-major as float4
  int tid = threadIdx.x;
  if (tid < 64) sWB[tid] = make_float4(W1[tid], W1[64 + tid], b1[tid], 0.f);
  for (int i = tid; i < 512; i += 256) sW2[i] = ((const float4*)W2)[i];
  __syncthreads();
  int v = blockIdx.x * 256 + tid;
  if (v >= N_NODES) return;
  int beg = row_ptr[v], end = row_ptr[v + 1];
  float2 sv = s[v];
  float t0 = sv.x, t1 = sv.y;
  int k = beg;
  for (; k + 4 <= end; k += 4) {
    int u0 = csr_src[k], u1 = csr_src[k + 1], u2 = csr_src[k + 2], u3 = csr_src[k + 3];
    float2 a = s[u0], b = s[u1], c = s[u2], d = s[u3];
    t0 += (a.x + b.x) + (c.x + d.x);
    t1 += (a.y + b.y) + (c.y + d.y);
  }
  for (; k < end; ++k) {
    float2 su = s[csr_src[k]];
    t0 += su.x;
    t1 += su.y;
  }
  float dv = dis[v];
  t0 *= dv;
  t1 *= dv;
  float4 a4[8];
#pragma unroll
  for (int m = 0; m < 8; ++m) a4[m] = make_float4(0.f, 0.f, 0.f, 0.f);
  for (int j = 0; j < 64; ++j) {
    float4 wb = sWB[j];
    float r = fmaxf(fmaf(t0, wb.x, fmaf(t1, wb.y, wb.z)), 0.f);
#pragma unroll
    for (int m = 0; m < 8; ++m) {
      float4 w = sW2[j * 8 + m];
      a4[m].x = fmaf(r, w.x, a4[m].x);
      a4[m].y = fmaf(r, w.y, a4[m].y);
      a4[m].z = fmaf(r, w.z, a4[m].z);
      a4[m].w = fmaf(r, w.w, a4[m].w);
    }
  }
  int pk[16];
#pragma unroll
  for (int m = 0; m < 8; ++m) {
    __half2 h0 = __floats2half2_rn(a4[m].x * dv, a4[m].y * dv);
    __half2 h1 = __floats2half2_rn(a4[m].z * dv, a4[m].w * dv);
    pk[2 * m]     = *reinterpret_cast<int*>(&h0);
    pk[2 * m + 1] = *reinterpret_cast<int*>(&h1);
  }
  q_lo[v * 2]     = make_int4(pk[0], pk[1], pk[2], pk[3]);
  q_lo[v * 2 + 1] = make_int4(pk[4], pk[5], pk[6], pk[7]);
  q_hi[v * 2]     = make_int4(pk[8], pk[9], pk[10], pk[11]);
  q_hi[v * 2 + 1] = make_int4(pk[12], pk[13], pk[14], pk[15]);
}

// ---------- layer 2 + pooling, XCD-partitioned feature halves --------------
// wg w: half = (w&7)>>2 (XCDs 0-3 -> lo plane, 4-7 -> hi plane);
// sub-block (w>>3)*4+(w&3) covers 64 nodes. 8 lanes per node-row (half2/lane),
// 32 rowgroups per block, 2 nodes per rowgroup, 8-deep unrolled gather.
__global__ void k_layer2(const __half2* __restrict__ q_lo, const __half2* __restrict__ q_hi,
                         const float* __restrict__ dis, const int* __restrict__ row_ptr,
                         const int* __restrict__ csr_src, const int* __restrict__ batch,
                         float* __restrict__ pooled) {
  __shared__ float2 red[32][8];
  int w = blockIdx.x;
  int h = (w & 7) >> 2;
  int sub = (w >> 3) * 4 + (w & 3);
  if (sub >= NODEBLK) return;
  const __half2* q = h ? q_hi : q_lo;
  int t = threadIdx.x;
  int fp = t & 7;           // feature pair 0..7
  int rg = t >> 3;          // rowgroup 0..31
  int vb = sub * 64;
  int nlast = min(vb + 63, N_NODES - 1);
  bool uniform = (batch[vb] == batch[nlast]);
  int v0 = vb + rg * 2;
  int v1 = min(v0 + 2, N_NODES);
  float2 acc = make_float2(0.f, 0.f);
  int curg = (v0 < N_NODES) ? batch[v0] : -1;
  int obase = h * 16 + 2 * fp;
  for (int v = v0; v < v1; ++v) {
    if (!uniform) {
      int g = batch[v];
      if (g != curg) {
        atomicAdd(&pooled[curg * 32 + obase], acc.x);
        atomicAdd(&pooled[curg * 32 + obase + 1], acc.y);
        acc = make_float2(0.f, 0.f);
        curg = g;
      }
    }
    int e0 = row_ptr[v], e1 = row_ptr[v + 1];
    float2 z = __half22float2(q[v * 8 + fp]);
    int k = e0;
    for (; k + 8 <= e1; k += 8) {
      int u0 = csr_src[k],     u1 = csr_src[k + 1], u2 = csr_src[k + 2], u3 = csr_src[k + 3];
      int u4 = csr_src[k + 4], u5 = csr_src[k + 5], u6 = csr_src[k + 6], u7 = csr_src[k + 7];
      float2 f0 = __half22float2(q[u0 * 8 + fp]);
      float2 f1 = __half22float2(q[u1 * 8 + fp]);
      float2 f2 = __half22float2(q[u2 * 8 + fp]);
      float2 f3 = __half22float2(q[u3 * 8 + fp]);
      float2 f4 = __half22float2(q[u4 * 8 + fp]);
      float2 f5 = __half22float2(q[u5 * 8 + fp]);
      float2 f6 = __half22float2(q[u6 * 8 + fp]);
      float2 f7 = __half22float2(q[u7 * 8 + fp]);
      z.x += ((f0.x + f1.x) + (f2.x + f3.x)) + ((f4.x + f5.x) + (f6.x + f7.x));
      z.y += ((f0.y + f1.y) + (f2.y + f3.y)) + ((f4.y + f5.y) + (f6.y + f7.y));
    }
    for (; k + 4 <= e1; k += 4) {
      int u0 = csr_src[k], u1 = csr_src[k + 1], u2 = csr_src[k + 2], u3 = csr_src[k + 3];
      float2 f0 = __half22float2(q[u0 * 8 + fp]);
      float2 f1 = __half22float2(q[u1 * 8 + fp]);
      float2 f2 = __half22float2(q[u2 * 8 + fp]);
      float2 f3 = __half22float2(q[u3 * 8 + fp]);
      z.x += (f0.x + f1.x) + (f2.x + f3.x);
      z.y += (f0.y + f1.y) + (f2.y + f3.y);
    }
    for (; k < e1; ++k) {
      float2 f = __half22float2(q[csr_src[k] * 8 + fp]);
      z.x += f.x;
      z.y += f.y;
    }
    float dv = dis[v];
    acc.x = fmaf(z.x, dv, acc.x);
    acc.y = fmaf(z.y, dv, acc.y);
  }
  if (uniform) {
    red[rg][fp] = acc;
    __syncthreads();
    if (t < 8) {
      float2 ssum = make_float2(0.f, 0.f);
#pragma unroll
      for (int r = 0; r < 32; ++r) {
        ssum.x += red[r][t].x;
        ssum.y += red[r][t].y;
      }
      int g = batch[vb];
      atomicAdd(&pooled[g * 32 + h * 16 + 2 * t], ssum.x);
      atomicAdd(&pooled[g * 32 + h * 16 + 2 * t + 1], ssum.y);
    }
  } else if (curg >= 0) {
    atomicAdd(&pooled[curg * 32 + obase], acc.x);
    atomicAdd(&pooled[curg * 32 + obase + 1], acc.y);
  }
}

// ---------- final: mean + b2 ----------
__global__ void k_final(float* __restrict__ out, const int* __restrict__ gstart,
                        const float* __restrict__ b2) {
  int i = blockIdx.x * 256 + threadIdx.x;
  if (i < N_GRAPHS * 32) {
    int g = i >> 5, l = i & 31;
    int c = gstart[g + 1] - gstart[g];
    out[i] = (c > 0) ? out[i] / (float)c + b2[l] : 0.f;
  }
}

extern "C" void kernel_launch(void* const* d_in, const int* in_sizes, int n_in,
                              void* d_out, int out_size, void* d_ws, size_t ws_size,
                              hipStream_t stream) {
  (void)in_sizes; (void)n_in; (void)out_size; (void)ws_size;
  const float* x   = (const float*)d_in[0];
  const float* W1  = (const float*)d_in[1];
  const float* b1  = (const float*)d_in[2];
  const float* W2  = (const float*)d_in[3];
  const float* b2  = (const float*)d_in[4];
  const int* edge  = (const int*)d_in[5];
  const int* batch = (const int*)d_in[6];
  const int* src = edge;             // edge_index[0]
  const int* dst = edge + N_EDGES;   // edge_index[1]
  float* out = (float*)d_out;

  int* ws      = (int*)d_ws;
  int* gstart  = ws + OFF_GSTART;
  int* row_ptr = ws + OFF_ROWPTR;
  float* dis   = (float*)(ws + OFF_DIS);
  float2* s    = (float2*)(ws + OFF_S);
  int* csr_src = ws + OFF_CSR;
  int4* q_lo4  = (int4*)(ws + OFF_QLO);
  int4* q_hi4  = (int4*)(ws + OFF_QHI);
  int* bhist   = ws + OFF_BHIST;
  int* boffl   = ws + OFF_BOFFL;
  int* bsum    = ws + OFF_BSUM;
  int* bstart  = ws + OFF_BSTART;
  int* tmp     = ws + OFF_TMP;

  k_hist<<<NBLK, 256, 0, stream>>>(dst, bhist);
  k_scan_a<<<NBUCK, 256, 0, stream>>>(bhist, boffl, bsum, batch, gstart);
  k_scan_b<<<1, 512, 0, stream>>>(bsum, bstart, out);
  k_scatter<<<NBLK, 256, 0, stream>>>(src, dst, bstart, boffl, tmp);
  k_fine<<<NBUCK, 256, 0, stream>>>(tmp, bstart, x, csr_src, row_ptr, dis, s);
  k_layer1<<<(N_NODES + 255) / 256, 256, 0, stream>>>(s, dis, row_ptr, csr_src,
                                                      W1, b1, W2, q_lo4, q_hi4);
  const int n_wg2 = ((NODEBLK + 3) / 4) * 8;   // 3128
  k_layer2<<<n_wg2, 256, 0, stream>>>((const __half2*)q_lo4, (const __half2*)q_hi4,
                                      dis, row_ptr, csr_src, batch, out);
  k_final<<<8, 256, 0, stream>>>(out, gstart, b2);
}